// Round 3
// baseline (327.786 us; speedup 1.0000x reference)
//
#include <hip/hip_runtime.h>
#include <math.h>

// SigmaMoE bf16-MFMA version, round 3.
// x[4,2048,1024] f32, expert_sel[16,1024], keys[16,1024,256],
// values[16,256,1024], route_scale[1] -> out[4,2048,1024] f32.
//
// Pipeline:
//  route_conv: fused x->bf16 convert + fp32 routing logits + exact top-4
//              -> per-expert lists (pk = t*4+k), wtk weights
//  trans:      keys  -> keysT  bf16 [16][256][1024]
//  trans:      values-> valuesT bf16 [16][1024][256]
//  ffn<1>:     per-expert 64-token tiles, MFMA 16x16x32 bf16, XOR-swizzled LDS,
//              global_load_lds staging; unweighted bf16 rows -> scratch[pk]
//  combine:    out[t] = sum_k wtk[t*4+k] * scratch[t*4+k]   (fp32)

constexpr int NTOK = 8192;
constexpr int DM   = 1024;
constexpr int NE   = 16;
constexpr int EH   = 256;
constexpr int TK   = 4;
constexpr int CAP  = 8192;
constexpr int TM   = 64;

typedef __attribute__((ext_vector_type(8))) short short8;
typedef __attribute__((ext_vector_type(4))) float f32x4;

#define MFMA16(a, b, c) __builtin_amdgcn_mfma_f32_16x16x32_bf16(a, b, c, 0, 0, 0)

__device__ __forceinline__ void gload_lds16(const void* g, void* l) {
    __builtin_amdgcn_global_load_lds(
        (const __attribute__((address_space(1))) void*)g,
        (__attribute__((address_space(3))) void*)l, 16, 0, 0);
}

__device__ __forceinline__ unsigned short f2bf(float f) {
    union { float f; unsigned int u; } x; x.f = f;
    unsigned int r = x.u + 0x7fffu + ((x.u >> 16) & 1u);  // RNE
    return (unsigned short)(r >> 16);
}
__device__ __forceinline__ float bf2f(unsigned short b) {
    union { unsigned int u; float f; } x; x.u = ((unsigned int)b) << 16;
    return x.f;
}

// ---------------- fused convert + routing ----------------
// 1024 blocks x 256 threads; 8 tokens/block, 32 lanes per token.
// esel staged in LDS (64KB fp32). Exact fp32 logits + top-4.
__global__ __launch_bounds__(256) void route_conv_kernel(
    const float* __restrict__ x, const float* __restrict__ esel,
    const float* __restrict__ rscale,
    unsigned short* __restrict__ xb,
    int* __restrict__ counts, int* __restrict__ lpk,
    float* __restrict__ lw, float* __restrict__ wtk)
{
    __shared__ float Es[NE * DM];   // 64KB
    int tid = threadIdx.x;

    {   // stage esel: 4096 float4s
        const float4* src = (const float4*)esel;
        float4* dst = (float4*)Es;
        #pragma unroll
        for (int j = 0; j < 16; ++j) dst[tid + j * 256] = src[tid + j * 256];
    }
    __syncthreads();

    int t    = blockIdx.x * 8 + (tid >> 5);
    int l32  = tid & 31;

    float acc[NE];
    #pragma unroll
    for (int e = 0; e < NE; ++e) acc[e] = 0.f;

    const float4* x4 = (const float4*)(x + (size_t)t * DM);
    const float4* E4 = (const float4*)Es;
    #pragma unroll
    for (int i4 = 0; i4 < 8; ++i4) {
        int d4 = i4 * 32 + l32;
        float4 xv = x4[d4];
        ushort4 cb = { f2bf(xv.x), f2bf(xv.y), f2bf(xv.z), f2bf(xv.w) };
        *(ushort4*)(xb + (size_t)t * DM + d4 * 4) = cb;
        #pragma unroll
        for (int e = 0; e < NE; ++e) {
            float4 wv = E4[e * 256 + d4];
            acc[e] = fmaf(xv.x, wv.x, acc[e]);
            acc[e] = fmaf(xv.y, wv.y, acc[e]);
            acc[e] = fmaf(xv.z, wv.z, acc[e]);
            acc[e] = fmaf(xv.w, wv.w, acc[e]);
        }
    }

    // reduce across the 32-lane token group
    #pragma unroll
    for (int off = 16; off; off >>= 1)
        #pragma unroll
        for (int e = 0; e < NE; ++e)
            acc[e] += __shfl_xor(acc[e], off, 32);

    // sigmoid probs
    float p[NE];
    #pragma unroll
    for (int e = 0; e < NE; ++e) p[e] = 1.0f / (1.0f + expf(-acc[e]));

    // exact top-4, min-index tiebreak (strict >), no runtime reg indexing
    int   sel_e[TK];
    float sel_p[TK];
    float sum = 0.f;
    #pragma unroll
    for (int k = 0; k < TK; ++k) {
        float best = -INFINITY; int be = NE;
        #pragma unroll
        for (int e = 0; e < NE; ++e) {
            bool take = p[e] > best;
            best = take ? p[e] : best;
            be   = take ? e    : be;
        }
        sel_e[k] = be; sel_p[k] = best; sum += best;
        #pragma unroll
        for (int e = 0; e < NE; ++e) p[e] = (e == be) ? -INFINITY : p[e];
    }

    if (l32 == 0) {
        float wsc = rscale[0] / fmaxf(sum, 1e-9f);
        #pragma unroll
        for (int k = 0; k < TK; ++k) {
            int ex = sel_e[k];
            int slot = atomicAdd(&counts[ex], 1);
            int pk = t * TK + k;
            float wv = sel_p[k] * wsc;
            lpk[ex * CAP + slot] = pk;
            lw[ex * CAP + slot]  = wv;
            wtk[pk] = wv;
        }
    }
}

// in [E][R][C] f32 -> out [E][C][R] bf16
__global__ __launch_bounds__(256) void trans_kernel(
    const float* __restrict__ in, unsigned short* __restrict__ outp, int R, int C)
{
    __shared__ float T[32][33];
    int e = blockIdx.z;
    int r0 = blockIdx.y * 32, c0 = blockIdx.x * 32;
    int ri = threadIdx.x >> 3, cq = threadIdx.x & 7;
    float4 v = *(const float4*)(in + ((size_t)e * R + r0 + ri) * C + c0 + cq * 4);
    T[ri][cq * 4 + 0] = v.x; T[ri][cq * 4 + 1] = v.y;
    T[ri][cq * 4 + 2] = v.z; T[ri][cq * 4 + 3] = v.w;
    __syncthreads();
    int ci = threadIdx.x >> 3, rq = threadIdx.x & 7;
    ushort4 o = { f2bf(T[rq * 4 + 0][ci]), f2bf(T[rq * 4 + 1][ci]),
                  f2bf(T[rq * 4 + 2][ci]), f2bf(T[rq * 4 + 3][ci]) };
    *(ushort4*)(outp + ((size_t)e * C + c0 + ci) * R + r0 + rq * 4) = o;
}

// ---------------- FFN (MFMA) ----------------
// block: 256 threads (4 waves); per block: expert e, 64 tokens.
// LDS (all bf16, XOR-swizzled byte ^= (row&7)<<4):
//   Xs [64][64]   8KB   x tile
//   KV [256][64] 32KB   keysT / valuesT k-slice
//   Ss [64][256] 32KB   relu scores
template<int USE_SCRATCH>
__global__ __launch_bounds__(256, 2) void ffn_kernel(
    const unsigned short* __restrict__ xb,
    const unsigned short* __restrict__ ktb,   // [16][256][1024]
    const unsigned short* __restrict__ vtb,   // [16][1024][256]
    const int* __restrict__ counts, const int* __restrict__ lpk,
    const float* __restrict__ lw,
    unsigned short* __restrict__ scratch,     // [32769][1024] bf16
    float* __restrict__ out)
{
    int e   = blockIdx.y;
    int cnt = counts[e];
    int t0  = blockIdx.x * TM;
    if (t0 >= cnt) return;

    __shared__ __align__(16) char L[74496];
    char* Xs = L;                // 8KB
    char* KV = L + 8192;         // 32KB
    char* Ss = L + 40960;        // 32KB
    int*   stok = (int*)(L + 73728);
    int*   spk  = (int*)(L + 73984);
    float* sw   = (float*)(L + 74240);

    int tid  = threadIdx.x;
    int lane = tid & 63;
    int w    = tid >> 6;

    if (tid < TM) {
        int s = t0 + tid;
        if (s < cnt) {
            int pk = lpk[e * CAP + s];
            stok[tid] = pk >> 2; spk[tid] = pk; sw[tid] = lw[e * CAP + s];
        } else {
            stok[tid] = 0; spk[tid] = USE_SCRATCH ? (NTOK * TK) : 0; sw[tid] = 0.f;
        }
    }
    __syncthreads();

    f32x4 zero = {0.f, 0.f, 0.f, 0.f};
    f32x4 acc[4][4];
    #pragma unroll
    for (int mi = 0; mi < 4; ++mi)
        #pragma unroll
        for (int ni = 0; ni < 4; ++ni) acc[mi][ni] = zero;

    // ---- phase 1: S = relu(X @ K_e), S[64][256] ----
    for (int kc = 0; kc < DM; kc += 64) {
        #pragma unroll
        for (int c = 0; c < 2; ++c) {          // Xs rows [w*16, +16)
            int base = (w * 16 + c * 8) * 128;
            int P = base + lane * 16;
            int row = P >> 7;
            int A = P ^ ((row & 7) << 4);
            const unsigned short* src =
                xb + (size_t)stok[A >> 7] * DM + kc + ((A & 127) >> 1);
            gload_lds16(src, Xs + base);
        }
        #pragma unroll
        for (int c = 0; c < 8; ++c) {          // KsT rows [w*64, +64)
            int base = (w * 64 + c * 8) * 128;
            int P = base + lane * 16;
            int row = P >> 7;
            int A = P ^ ((row & 7) << 4);
            const unsigned short* src =
                ktb + ((size_t)e * EH + (A >> 7)) * DM + kc + ((A & 127) >> 1);
            gload_lds16(src, KV + base);
        }
        __syncthreads();
        #pragma unroll
        for (int kk = 0; kk < 2; ++kk) {
            short8 a[4], b[4];
            #pragma unroll
            for (int mi = 0; mi < 4; ++mi) {
                int row = mi * 16 + (lane & 15);
                int A = row * 128 + (kk * 32 + (lane >> 4) * 8) * 2;
                a[mi] = *(const short8*)(Xs + (A ^ ((row & 7) << 4)));
            }
            #pragma unroll
            for (int ni = 0; ni < 4; ++ni) {
                int row = w * 64 + ni * 16 + (lane & 15);
                int A = row * 128 + (kk * 32 + (lane >> 4) * 8) * 2;
                b[ni] = *(const short8*)(KV + (A ^ ((row & 7) << 4)));
            }
            #pragma unroll
            for (int mi = 0; mi < 4; ++mi)
                #pragma unroll
                for (int ni = 0; ni < 4; ++ni)
                    acc[mi][ni] = MFMA16(a[mi], b[ni], acc[mi][ni]);
        }
        __syncthreads();
    }

    // relu -> Ss (bf16, swizzled); D layout: col=lane&15, row=(lane>>4)*4+r
    #pragma unroll
    for (int mi = 0; mi < 4; ++mi)
        #pragma unroll
        for (int ni = 0; ni < 4; ++ni) {
            f32x4 v = acc[mi][ni];
            #pragma unroll
            for (int r = 0; r < 4; ++r) {
                int row = mi * 16 + (lane >> 4) * 4 + r;
                int col = w * 64 + ni * 16 + (lane & 15);
                int A = row * 512 + col * 2;
                *(unsigned short*)(Ss + (A ^ ((row & 7) << 4))) =
                    f2bf(fmaxf(v[r], 0.f));
            }
        }
    __syncthreads();

    // ---- phase 2: O = S @ V_e, in 4 n-chunks of 256 ----
    for (int nb = 0; nb < 4; ++nb) {
        f32x4 acc2[4][4];
        #pragma unroll
        for (int mi = 0; mi < 4; ++mi)
            #pragma unroll
            for (int ni = 0; ni < 4; ++ni) acc2[mi][ni] = zero;

        for (int kc = 0; kc < EH; kc += 64) {
            #pragma unroll
            for (int c = 0; c < 8; ++c) {      // VsT rows [w*64, +64)
                int base = (w * 64 + c * 8) * 128;
                int P = base + lane * 16;
                int row = P >> 7;
                int A = P ^ ((row & 7) << 4);
                const unsigned short* src =
                    vtb + ((size_t)e * DM + nb * 256 + (A >> 7)) * EH + kc + ((A & 127) >> 1);
                gload_lds16(src, KV + base);
            }
            __syncthreads();
            #pragma unroll
            for (int kk = 0; kk < 2; ++kk) {
                short8 a[4], b[4];
                #pragma unroll
                for (int mi = 0; mi < 4; ++mi) {
                    int row = mi * 16 + (lane & 15);
                    int A = row * 512 + (kc + kk * 32 + (lane >> 4) * 8) * 2;
                    a[mi] = *(const short8*)(Ss + (A ^ ((row & 7) << 4)));
                }
                #pragma unroll
                for (int ni = 0; ni < 4; ++ni) {
                    int row = w * 64 + ni * 16 + (lane & 15);
                    int A = row * 128 + (kk * 32 + (lane >> 4) * 8) * 2;
                    b[ni] = *(const short8*)(KV + (A ^ ((row & 7) << 4)));
                }
                #pragma unroll
                for (int mi = 0; mi < 4; ++mi)
                    #pragma unroll
                    for (int ni = 0; ni < 4; ++ni)
                        acc2[mi][ni] = MFMA16(a[mi], b[ni], acc2[mi][ni]);
            }
            __syncthreads();
        }

        #pragma unroll
        for (int mi = 0; mi < 4; ++mi)
            #pragma unroll
            for (int ni = 0; ni < 4; ++ni) {
                f32x4 v = acc2[mi][ni];
                #pragma unroll
                for (int r = 0; r < 4; ++r) {
                    int slot = mi * 16 + (lane >> 4) * 4 + r;
                    int d = nb * 256 + w * 64 + ni * 16 + (lane & 15);
                    if (USE_SCRATCH) {
                        scratch[(size_t)spk[slot] * DM + d] = f2bf(v[r]);
                    } else {
                        atomicAdd(out + (size_t)stok[slot] * DM + d, sw[slot] * v[r]);
                    }
                }
            }
    }
}

// ---------------- combine ----------------
__global__ __launch_bounds__(256) void combine_kernel(
    const unsigned short* __restrict__ scratch, const float* __restrict__ wtk,
    float* __restrict__ out)
{
    int t  = blockIdx.x * 2 + (threadIdx.x >> 7);
    int d0 = (threadIdx.x & 127) * 8;
    float o[8] = {0.f, 0.f, 0.f, 0.f, 0.f, 0.f, 0.f, 0.f};
    #pragma unroll
    for (int k = 0; k < TK; ++k) {
        float wv = wtk[t * TK + k];
        uint4 q = *(const uint4*)(scratch + (size_t)(t * TK + k) * DM + d0);
        unsigned int us[4] = {q.x, q.y, q.z, q.w};
        #pragma unroll
        for (int j = 0; j < 4; ++j) {
            o[j * 2 + 0] = fmaf(wv, bf2f((unsigned short)(us[j] & 0xffff)), o[j * 2 + 0]);
            o[j * 2 + 1] = fmaf(wv, bf2f((unsigned short)(us[j] >> 16)),    o[j * 2 + 1]);
        }
    }
    float4 w0 = {o[0], o[1], o[2], o[3]}, w1 = {o[4], o[5], o[6], o[7]};
    *(float4*)(out + (size_t)t * DM + d0)     = w0;
    *(float4*)(out + (size_t)t * DM + d0 + 4) = w1;
}

extern "C" void kernel_launch(void* const* d_in, const int* in_sizes, int n_in,
                              void* d_out, int out_size, void* d_ws, size_t ws_size,
                              hipStream_t stream) {
    const float* x      = (const float*)d_in[0];
    const float* esel   = (const float*)d_in[1];
    const float* keys   = (const float*)d_in[2];
    const float* values = (const float*)d_in[3];
    const float* rscale = (const float*)d_in[4];
    float* out = (float*)d_out;

    char* ws = (char*)d_ws;
    size_t o = 0;
    auto alloc = [&](size_t sz) { size_t r = o; o = (o + sz + 255) & ~(size_t)255; return r; };
    size_t o_counts = alloc(NE * 4);
    size_t o_lpk    = alloc((size_t)NE * CAP * 4);
    size_t o_lw     = alloc((size_t)NE * CAP * 4);
    size_t o_wtk    = alloc((size_t)NTOK * TK * 4);
    size_t o_xb     = alloc((size_t)NTOK * DM * 2);
    size_t o_ktb    = alloc((size_t)NE * EH * DM * 2);
    size_t o_vtb    = alloc((size_t)NE * DM * EH * 2);
    size_t need_small = o;
    size_t o_scr    = alloc(((size_t)NTOK * TK + TM) * DM * 2);
    size_t need_full = o;

    int*            counts  = (int*)(ws + o_counts);
    int*            lpk     = (int*)(ws + o_lpk);
    float*          lw      = (float*)(ws + o_lw);
    float*          wtk     = (float*)(ws + o_wtk);
    unsigned short* xb      = (unsigned short*)(ws + o_xb);
    unsigned short* ktb     = (unsigned short*)(ws + o_ktb);
    unsigned short* vtb     = (unsigned short*)(ws + o_vtb);
    unsigned short* scratch = (unsigned short*)(ws + o_scr);

    bool use_scratch = ws_size >= need_full;
    (void)need_small;

    hipMemsetAsync(counts, 0, 256, stream);
    if (!use_scratch)
        hipMemsetAsync(d_out, 0, (size_t)out_size * sizeof(float), stream);

    route_conv_kernel<<<NTOK / 8, 256, 0, stream>>>(x, esel, rscale, xb,
                                                    counts, lpk, lw, wtk);
    trans_kernel<<<dim3(EH / 32, DM / 32, NE), 256, 0, stream>>>(keys, ktb, DM, EH);
    trans_kernel<<<dim3(DM / 32, EH / 32, NE), 256, 0, stream>>>(values, vtb, EH, DM);

    if (use_scratch) {
        ffn_kernel<1><<<dim3(CAP / TM, NE), 256, 0, stream>>>(
            xb, ktb, vtb, counts, lpk, lw, scratch, out);
        combine_kernel<<<NTOK / 2, 256, 0, stream>>>(scratch, wtk, out);
    } else {
        ffn_kernel<0><<<dim3(CAP / TM, NE), 256, 0, stream>>>(
            xb, ktb, vtb, counts, lpk, lw, scratch, out);
    }
}

// Round 4
// 147.838 us; speedup vs baseline: 2.2172x; 2.2172x over previous
//
#include <hip/hip_runtime.h>
#include <math.h>

// SigmaMoE bf16-MFMA version, round 4.
// x[4,2048,1024] f32, expert_sel[16,1024], keys[16,1024,256],
// values[16,256,1024], route_scale[1] -> out[4,2048,1024] f32.
//
// Pipeline (NO global atomics anywhere):
//  route_conv: fused x->bf16 convert + fp32 routing logits + exact top-4
//              -> sel4[t] (int4), wtk[t*4+k] weights, xb
//  compact:    per-expert list build via ballot-scan (16 blocks, deterministic)
//  trans:      keys  -> keysT  bf16 [16][256][1024]
//  trans:      values-> valuesT bf16 [16][1024][256]
//  ffn<1>:     per-expert 64-token tiles, MFMA 16x16x32 bf16, XOR-swizzled LDS,
//              global_load_lds staging; unweighted bf16 rows -> scratch[pk]
//  combine:    out[t] = sum_k wtk[t*4+k] * scratch[t*4+k]   (fp32)

constexpr int NTOK = 8192;
constexpr int DM   = 1024;
constexpr int NE   = 16;
constexpr int EH   = 256;
constexpr int TK   = 4;
constexpr int CAP  = 8192;
constexpr int TM   = 64;

typedef __attribute__((ext_vector_type(8))) short short8;
typedef __attribute__((ext_vector_type(4))) float f32x4;

#define MFMA16(a, b, c) __builtin_amdgcn_mfma_f32_16x16x32_bf16(a, b, c, 0, 0, 0)

__device__ __forceinline__ void gload_lds16(const void* g, void* l) {
    __builtin_amdgcn_global_load_lds(
        (const __attribute__((address_space(1))) void*)g,
        (__attribute__((address_space(3))) void*)l, 16, 0, 0);
}

__device__ __forceinline__ unsigned short f2bf(float f) {
    union { float f; unsigned int u; } x; x.f = f;
    unsigned int r = x.u + 0x7fffu + ((x.u >> 16) & 1u);  // RNE
    return (unsigned short)(r >> 16);
}
__device__ __forceinline__ float bf2f(unsigned short b) {
    union { unsigned int u; float f; } x; x.u = ((unsigned int)b) << 16;
    return x.f;
}

// ---------------- fused convert + routing (atomic-free) ----------------
// 1024 blocks x 256 threads; 8 tokens/block, 32 lanes per token.
// esel staged in LDS (64KB fp32). Exact fp32 logits + prob top-4
// (strict >, lowest-index-first on ties == jax.lax.top_k stability).
__global__ __launch_bounds__(256) void route_conv_kernel(
    const float* __restrict__ x, const float* __restrict__ esel,
    const float* __restrict__ rscale,
    unsigned short* __restrict__ xb,
    int4* __restrict__ sel4, float* __restrict__ wtk)
{
    __shared__ float Es[NE * DM];   // 64KB
    int tid = threadIdx.x;

    {   // stage esel: 4096 float4s
        const float4* src = (const float4*)esel;
        float4* dst = (float4*)Es;
        #pragma unroll
        for (int j = 0; j < 16; ++j) dst[tid + j * 256] = src[tid + j * 256];
    }
    __syncthreads();

    int t    = blockIdx.x * 8 + (tid >> 5);
    int l32  = tid & 31;

    float acc[NE];
    #pragma unroll
    for (int e = 0; e < NE; ++e) acc[e] = 0.f;

    const float4* x4 = (const float4*)(x + (size_t)t * DM);
    const float4* E4 = (const float4*)Es;
    #pragma unroll
    for (int i4 = 0; i4 < 8; ++i4) {
        int d4 = i4 * 32 + l32;
        float4 xv = x4[d4];
        ushort4 cb = { f2bf(xv.x), f2bf(xv.y), f2bf(xv.z), f2bf(xv.w) };
        *(ushort4*)(xb + (size_t)t * DM + d4 * 4) = cb;
        #pragma unroll
        for (int e = 0; e < NE; ++e) {
            float4 wv = E4[e * 256 + d4];
            acc[e] = fmaf(xv.x, wv.x, acc[e]);
            acc[e] = fmaf(xv.y, wv.y, acc[e]);
            acc[e] = fmaf(xv.z, wv.z, acc[e]);
            acc[e] = fmaf(xv.w, wv.w, acc[e]);
        }
    }

    // reduce across the 32-lane token group
    #pragma unroll
    for (int off = 16; off; off >>= 1)
        #pragma unroll
        for (int e = 0; e < NE; ++e)
            acc[e] += __shfl_xor(acc[e], off, 32);

    if (l32 == 0) {
        // sigmoid probs
        float p[NE];
        #pragma unroll
        for (int e = 0; e < NE; ++e) p[e] = 1.0f / (1.0f + expf(-acc[e]));

        int   sel_e[TK];
        float sel_p[TK];
        float sum = 0.f;
        #pragma unroll
        for (int k = 0; k < TK; ++k) {
            float best = -INFINITY; int be = NE;
            #pragma unroll
            for (int e = 0; e < NE; ++e) {
                bool take = p[e] > best;
                best = take ? p[e] : best;
                be   = take ? e    : be;
            }
            sel_e[k] = be; sel_p[k] = best; sum += best;
            #pragma unroll
            for (int e = 0; e < NE; ++e) p[e] = (e == be) ? -INFINITY : p[e];
        }

        float wsc = rscale[0] / fmaxf(sum, 1e-9f);
        int4 s = { sel_e[0], sel_e[1], sel_e[2], sel_e[3] };
        sel4[t] = s;
        float4 wv = { sel_p[0] * wsc, sel_p[1] * wsc,
                      sel_p[2] * wsc, sel_p[3] * wsc };
        *(float4*)(wtk + t * TK) = wv;
    }
}

// ---------------- compact: per-expert lists, atomic-free ----------------
// 16 blocks (one per expert) x 1024 threads; ballot-scan compaction.
__global__ __launch_bounds__(1024) void compact_kernel(
    const int4* __restrict__ sel4, int* __restrict__ counts,
    int* __restrict__ lpk)
{
    __shared__ int wsum[16];
    int e    = blockIdx.x;
    int tid  = threadIdx.x;
    int w    = tid >> 6;
    int lane = tid & 63;

    int base = 0;
    for (int c = 0; c < NTOK; c += 1024) {
        int t = c + tid;
        int4 s = sel4[t];
        int k = -1;
        if      (s.x == e) k = 0;
        else if (s.y == e) k = 1;
        else if (s.z == e) k = 2;
        else if (s.w == e) k = 3;
        unsigned long long m = __ballot(k >= 0);
        int rank = __popcll(m & ((1ull << lane) - 1ull));
        if (lane == 63) wsum[w] = __popcll(m);
        __syncthreads();
        int prefix = 0, total = 0;
        #pragma unroll
        for (int i = 0; i < 16; ++i) {
            int v = wsum[i];
            prefix += (i < w) ? v : 0;
            total  += v;
        }
        if (k >= 0) lpk[e * CAP + base + prefix + rank] = t * TK + k;
        base += total;
        __syncthreads();
    }
    if (tid == 0) counts[e] = base;
}

// in [E][R][C] f32 -> out [E][C][R] bf16
__global__ __launch_bounds__(256) void trans_kernel(
    const float* __restrict__ in, unsigned short* __restrict__ outp, int R, int C)
{
    __shared__ float T[32][33];
    int e = blockIdx.z;
    int r0 = blockIdx.y * 32, c0 = blockIdx.x * 32;
    int ri = threadIdx.x >> 3, cq = threadIdx.x & 7;
    float4 v = *(const float4*)(in + ((size_t)e * R + r0 + ri) * C + c0 + cq * 4);
    T[ri][cq * 4 + 0] = v.x; T[ri][cq * 4 + 1] = v.y;
    T[ri][cq * 4 + 2] = v.z; T[ri][cq * 4 + 3] = v.w;
    __syncthreads();
    int ci = threadIdx.x >> 3, rq = threadIdx.x & 7;
    ushort4 o = { f2bf(T[rq * 4 + 0][ci]), f2bf(T[rq * 4 + 1][ci]),
                  f2bf(T[rq * 4 + 2][ci]), f2bf(T[rq * 4 + 3][ci]) };
    *(ushort4*)(outp + ((size_t)e * C + c0 + ci) * R + r0 + rq * 4) = o;
}

// ---------------- FFN (MFMA) ----------------
// block: 256 threads (4 waves); per block: expert e, 64 tokens.
// LDS (all bf16, XOR-swizzled byte ^= (row&7)<<4):
//   Xs [64][64]   8KB   x tile
//   KV [256][64] 32KB   keysT / valuesT k-slice
//   Ss [64][256] 32KB   relu scores
template<int USE_SCRATCH>
__global__ __launch_bounds__(256, 2) void ffn_kernel(
    const unsigned short* __restrict__ xb,
    const unsigned short* __restrict__ ktb,   // [16][256][1024]
    const unsigned short* __restrict__ vtb,   // [16][1024][256]
    const int* __restrict__ counts, const int* __restrict__ lpk,
    const float* __restrict__ wtk,
    unsigned short* __restrict__ scratch,     // [32769][1024] bf16
    float* __restrict__ out)
{
    int e   = blockIdx.y;
    int cnt = counts[e];
    int t0  = blockIdx.x * TM;
    if (t0 >= cnt) return;

    __shared__ __align__(16) char L[74496];
    char* Xs = L;                // 8KB
    char* KV = L + 8192;         // 32KB
    char* Ss = L + 40960;        // 32KB
    int*   stok = (int*)(L + 73728);
    int*   spk  = (int*)(L + 73984);
    float* sw   = (float*)(L + 74240);

    int tid  = threadIdx.x;
    int lane = tid & 63;
    int w    = tid >> 6;

    if (tid < TM) {
        int s = t0 + tid;
        if (s < cnt) {
            int pk = lpk[e * CAP + s];
            stok[tid] = pk >> 2; spk[tid] = pk; sw[tid] = wtk[pk];
        } else {
            stok[tid] = 0; spk[tid] = USE_SCRATCH ? (NTOK * TK) : 0; sw[tid] = 0.f;
        }
    }
    __syncthreads();

    f32x4 zero = {0.f, 0.f, 0.f, 0.f};
    f32x4 acc[4][4];
    #pragma unroll
    for (int mi = 0; mi < 4; ++mi)
        #pragma unroll
        for (int ni = 0; ni < 4; ++ni) acc[mi][ni] = zero;

    // ---- phase 1: S = relu(X @ K_e), S[64][256] ----
    for (int kc = 0; kc < DM; kc += 64) {
        #pragma unroll
        for (int c = 0; c < 2; ++c) {          // Xs rows [w*16, +16)
            int base = (w * 16 + c * 8) * 128;
            int P = base + lane * 16;
            int row = P >> 7;
            int A = P ^ ((row & 7) << 4);
            const unsigned short* src =
                xb + (size_t)stok[A >> 7] * DM + kc + ((A & 127) >> 1);
            gload_lds16(src, Xs + base);
        }
        #pragma unroll
        for (int c = 0; c < 8; ++c) {          // KsT rows [w*64, +64)
            int base = (w * 64 + c * 8) * 128;
            int P = base + lane * 16;
            int row = P >> 7;
            int A = P ^ ((row & 7) << 4);
            const unsigned short* src =
                ktb + ((size_t)e * EH + (A >> 7)) * DM + kc + ((A & 127) >> 1);
            gload_lds16(src, KV + base);
        }
        __syncthreads();
        #pragma unroll
        for (int kk = 0; kk < 2; ++kk) {
            short8 a[4], b[4];
            #pragma unroll
            for (int mi = 0; mi < 4; ++mi) {
                int row = mi * 16 + (lane & 15);
                int A = row * 128 + (kk * 32 + (lane >> 4) * 8) * 2;
                a[mi] = *(const short8*)(Xs + (A ^ ((row & 7) << 4)));
            }
            #pragma unroll
            for (int ni = 0; ni < 4; ++ni) {
                int row = w * 64 + ni * 16 + (lane & 15);
                int A = row * 128 + (kk * 32 + (lane >> 4) * 8) * 2;
                b[ni] = *(const short8*)(KV + (A ^ ((row & 7) << 4)));
            }
            #pragma unroll
            for (int mi = 0; mi < 4; ++mi)
                #pragma unroll
                for (int ni = 0; ni < 4; ++ni)
                    acc[mi][ni] = MFMA16(a[mi], b[ni], acc[mi][ni]);
        }
        __syncthreads();
    }

    // relu -> Ss (bf16, swizzled); D layout: col=lane&15, row=(lane>>4)*4+r
    #pragma unroll
    for (int mi = 0; mi < 4; ++mi)
        #pragma unroll
        for (int ni = 0; ni < 4; ++ni) {
            f32x4 v = acc[mi][ni];
            #pragma unroll
            for (int r = 0; r < 4; ++r) {
                int row = mi * 16 + (lane >> 4) * 4 + r;
                int col = w * 64 + ni * 16 + (lane & 15);
                int A = row * 512 + col * 2;
                *(unsigned short*)(Ss + (A ^ ((row & 7) << 4))) =
                    f2bf(fmaxf(v[r], 0.f));
            }
        }
    __syncthreads();

    // ---- phase 2: O = S @ V_e, in 4 n-chunks of 256 ----
    for (int nb = 0; nb < 4; ++nb) {
        f32x4 acc2[4][4];
        #pragma unroll
        for (int mi = 0; mi < 4; ++mi)
            #pragma unroll
            for (int ni = 0; ni < 4; ++ni) acc2[mi][ni] = zero;

        for (int kc = 0; kc < EH; kc += 64) {
            #pragma unroll
            for (int c = 0; c < 8; ++c) {      // VsT rows [w*64, +64)
                int base = (w * 64 + c * 8) * 128;
                int P = base + lane * 16;
                int row = P >> 7;
                int A = P ^ ((row & 7) << 4);
                const unsigned short* src =
                    vtb + ((size_t)e * DM + nb * 256 + (A >> 7)) * EH + kc + ((A & 127) >> 1);
                gload_lds16(src, KV + base);
            }
            __syncthreads();
            #pragma unroll
            for (int kk = 0; kk < 2; ++kk) {
                short8 a[4], b[4];
                #pragma unroll
                for (int mi = 0; mi < 4; ++mi) {
                    int row = mi * 16 + (lane & 15);
                    int A = row * 512 + (kc + kk * 32 + (lane >> 4) * 8) * 2;
                    a[mi] = *(const short8*)(Ss + (A ^ ((row & 7) << 4)));
                }
                #pragma unroll
                for (int ni = 0; ni < 4; ++ni) {
                    int row = w * 64 + ni * 16 + (lane & 15);
                    int A = row * 128 + (kk * 32 + (lane >> 4) * 8) * 2;
                    b[ni] = *(const short8*)(KV + (A ^ ((row & 7) << 4)));
                }
                #pragma unroll
                for (int mi = 0; mi < 4; ++mi)
                    #pragma unroll
                    for (int ni = 0; ni < 4; ++ni)
                        acc2[mi][ni] = MFMA16(a[mi], b[ni], acc2[mi][ni]);
            }
            __syncthreads();
        }

        #pragma unroll
        for (int mi = 0; mi < 4; ++mi)
            #pragma unroll
            for (int ni = 0; ni < 4; ++ni) {
                f32x4 v = acc2[mi][ni];
                #pragma unroll
                for (int r = 0; r < 4; ++r) {
                    int slot = mi * 16 + (lane >> 4) * 4 + r;
                    int d = nb * 256 + w * 64 + ni * 16 + (lane & 15);
                    if (USE_SCRATCH) {
                        scratch[(size_t)spk[slot] * DM + d] = f2bf(v[r]);
                    } else {
                        atomicAdd(out + (size_t)stok[slot] * DM + d, sw[slot] * v[r]);
                    }
                }
            }
    }
}

// ---------------- combine ----------------
__global__ __launch_bounds__(256) void combine_kernel(
    const unsigned short* __restrict__ scratch, const float* __restrict__ wtk,
    float* __restrict__ out)
{
    int t  = blockIdx.x * 2 + (threadIdx.x >> 7);
    int d0 = (threadIdx.x & 127) * 8;
    float o[8] = {0.f, 0.f, 0.f, 0.f, 0.f, 0.f, 0.f, 0.f};
    #pragma unroll
    for (int k = 0; k < TK; ++k) {
        float wv = wtk[t * TK + k];
        uint4 q = *(const uint4*)(scratch + (size_t)(t * TK + k) * DM + d0);
        unsigned int us[4] = {q.x, q.y, q.z, q.w};
        #pragma unroll
        for (int j = 0; j < 4; ++j) {
            o[j * 2 + 0] = fmaf(wv, bf2f((unsigned short)(us[j] & 0xffff)), o[j * 2 + 0]);
            o[j * 2 + 1] = fmaf(wv, bf2f((unsigned short)(us[j] >> 16)),    o[j * 2 + 1]);
        }
    }
    float4 w0 = {o[0], o[1], o[2], o[3]}, w1 = {o[4], o[5], o[6], o[7]};
    *(float4*)(out + (size_t)t * DM + d0)     = w0;
    *(float4*)(out + (size_t)t * DM + d0 + 4) = w1;
}

extern "C" void kernel_launch(void* const* d_in, const int* in_sizes, int n_in,
                              void* d_out, int out_size, void* d_ws, size_t ws_size,
                              hipStream_t stream) {
    const float* x      = (const float*)d_in[0];
    const float* esel   = (const float*)d_in[1];
    const float* keys   = (const float*)d_in[2];
    const float* values = (const float*)d_in[3];
    const float* rscale = (const float*)d_in[4];
    float* out = (float*)d_out;

    char* ws = (char*)d_ws;
    size_t o = 0;
    auto alloc = [&](size_t sz) { size_t r = o; o = (o + sz + 255) & ~(size_t)255; return r; };
    size_t o_counts = alloc(NE * 4);
    size_t o_lpk    = alloc((size_t)NE * CAP * 4);
    size_t o_sel4   = alloc((size_t)NTOK * 16);
    size_t o_wtk    = alloc((size_t)NTOK * TK * 4);
    size_t o_xb     = alloc((size_t)NTOK * DM * 2);
    size_t o_ktb    = alloc((size_t)NE * EH * DM * 2);
    size_t o_vtb    = alloc((size_t)NE * DM * EH * 2);
    size_t o_scr    = alloc(((size_t)NTOK * TK + TM) * DM * 2);
    size_t need_full = o;

    int*            counts  = (int*)(ws + o_counts);
    int*            lpk     = (int*)(ws + o_lpk);
    int4*           sel4    = (int4*)(ws + o_sel4);
    float*          wtk     = (float*)(ws + o_wtk);
    unsigned short* xb      = (unsigned short*)(ws + o_xb);
    unsigned short* ktb     = (unsigned short*)(ws + o_ktb);
    unsigned short* vtb     = (unsigned short*)(ws + o_vtb);
    unsigned short* scratch = (unsigned short*)(ws + o_scr);

    bool use_scratch = ws_size >= need_full;

    if (!use_scratch)
        hipMemsetAsync(d_out, 0, (size_t)out_size * sizeof(float), stream);

    route_conv_kernel<<<NTOK / 8, 256, 0, stream>>>(x, esel, rscale, xb,
                                                    sel4, wtk);
    compact_kernel<<<NE, 1024, 0, stream>>>(sel4, counts, lpk);
    trans_kernel<<<dim3(EH / 32, DM / 32, NE), 256, 0, stream>>>(keys, ktb, DM, EH);
    trans_kernel<<<dim3(DM / 32, EH / 32, NE), 256, 0, stream>>>(values, vtb, EH, DM);

    if (use_scratch) {
        ffn_kernel<1><<<dim3(CAP / TM, NE), 256, 0, stream>>>(
            xb, ktb, vtb, counts, lpk, wtk, scratch, out);
        combine_kernel<<<NTOK / 2, 256, 0, stream>>>(scratch, wtk, out);
    } else {
        ffn_kernel<0><<<dim3(CAP / TM, NE), 256, 0, stream>>>(
            xb, ktb, vtb, counts, lpk, wtk, scratch, out);
    }
}